// Round 7
// baseline (269.701 us; speedup 1.0000x reference)
//
#include <hip/hip_runtime.h>
#include <math.h>

#define NB 2
#define NN 256
#define FF 64
#define HH 64
#define NHEADS 4
#define KK 50
#define CC 256

constexpr int BN = NB * NN;          // 512
constexpr int NPAIR = NB * NN * NN;  // 131072

typedef __attribute__((ext_vector_type(8))) short bf16x8;
typedef __attribute__((ext_vector_type(4))) float f32x4v;

__device__ __forceinline__ float siluf(float v) { return v / (1.f + __expf(-v)); }
__device__ __forceinline__ float sigmoidf_(float v) { return 1.f / (1.f + __expf(-v)); }
__device__ __forceinline__ float tanh_fast(float x) {
    x = fminf(fmaxf(x, -15.f), 15.f);
    float e = __expf(2.f * x);
    return (e - 1.f) / (e + 1.f);
}
__device__ __forceinline__ unsigned short f2bf(float f) {
    union { float f; unsigned u; } v; v.f = f;
    unsigned r = v.u + 0x7fffu + ((v.u >> 16) & 1u);
    return (unsigned short)(r >> 16);
}
__device__ __forceinline__ float bf2f(short s) {
    union { unsigned u; float f; } v;
    v.u = ((unsigned)(unsigned short)s) << 16;
    return v.f;
}

// ---------------------------------------------------------------------------
// K0: per-node precompute (U,V from W_in halves; P,Q from W_o1 halves).
// ---------------------------------------------------------------------------
__global__ __launch_bounds__(64) void k0_node_pre(
    const float* __restrict__ h,
    const float* __restrict__ W_in, const float* __restrict__ b_in,
    const float* __restrict__ W_o1, const float* __restrict__ b_o1,
    float* __restrict__ U, float* __restrict__ V,
    float* __restrict__ P, float* __restrict__ Q)
{
    __shared__ float hh[64];
    const int bn = blockIdx.x;
    const int t = threadIdx.x;
    hh[t] = h[(size_t)bn * FF + t];
    __syncthreads();

    float accP = b_o1[t], accQ = 0.f;
#pragma unroll 8
    for (int k = 0; k < 64; k++) {
        float hv = hh[k];
        accP += hv * W_o1[k * HH + t];
        accQ += hv * W_o1[(64 + k) * HH + t];
    }
    P[(size_t)bn * 64 + t] = accP;
    Q[(size_t)bn * 64 + t] = accQ;

    if (t < KK) {
        float aU = b_in[t], aV = 0.f;
#pragma unroll 8
        for (int k = 0; k < 64; k++) {
            float hv = hh[k];
            aU += hv * W_in[k * KK + t];
            aV += hv * W_in[(64 + k) * KK + t];
        }
        U[(size_t)bn * 64 + t] = aU;
        V[(size_t)bn * 64 + t] = aV;
    }
}

// ---------------------------------------------------------------------------
// K0c: build bf16 B^T tables for k1's two MFMA GEMMs.
// ---------------------------------------------------------------------------
__global__ __launch_bounds__(256) void k0c_wtrans(
    const float* __restrict__ W_o1, const float* __restrict__ W_o2,
    unsigned short* __restrict__ Wo1T, unsigned short* __restrict__ Wo2T)
{
    int idx = blockIdx.x * 256 + threadIdx.x;   // 4096 total
    int n = idx >> 6, k = idx & 63;
    float v1 = (k < KK) ? W_o1[(128 + k) * HH + n]
             : (k == KK) ? W_o1[178 * HH + n] : 0.f;
    Wo1T[idx] = f2bf(v1);
    Wo2T[idx] = f2bf(W_o2[k * HH + n]);
}

// ---------------------------------------------------------------------------
// K0b: Wx [k][n] fp32 -> WxT [n][k] bf16 (for k3). Runs AFTER k2.
// ---------------------------------------------------------------------------
__global__ __launch_bounds__(256) void k0b_wxt(
    const float* __restrict__ Wx, unsigned short* __restrict__ WxT)
{
    int idx = blockIdx.x * 256 + threadIdx.x;   // 65536 total
    int n = idx >> 8, k = idx & 255;
    WxT[idx] = f2bf(Wx[k * 256 + n]);
}

// ---------------------------------------------------------------------------
// K1: edge model via bf16 MFMA (round-5 verified).
// ---------------------------------------------------------------------------
__global__ __launch_bounds__(256) void k1_edge_mfma(
    const float* __restrict__ x,
    const float* __restrict__ means, const float* __restrict__ betas,
    const float* __restrict__ U, const float* __restrict__ V,
    const float* __restrict__ P, const float* __restrict__ Q,
    const unsigned short* __restrict__ Wo1T, const unsigned short* __restrict__ Wo2T,
    const float* __restrict__ Ws, const float* __restrict__ bs,
    float* __restrict__ he_mtx, float* __restrict__ sem_logit,
    float* __restrict__ norm_g)
{
    __shared__ __align__(16) unsigned short A1[256 * 72];   // 36 KB
    __shared__ __align__(16) unsigned short A2[256 * 72];   // 36 KB
    __shared__ float nrm_s[256];
    __shared__ float en_s[256];

    const int tid = threadIdx.x;
    const int l = tid & 63;
    const int w = tid >> 6;
    const int lcol = l & 15;
    const int quad = l >> 4;
    const int bi = blockIdx.x;
    const int b = bi >> 8;
    const int i = bi & 255;
    const float* xb = x + (size_t)b * NN * 3;

    // ---- phase 0: per-j geometry (thread = j)
    {
        int j = tid;
        float dx0 = xb[j * 3 + 0] - xb[i * 3 + 0];
        float dx1 = xb[j * 3 + 1] - xb[i * 3 + 1];
        float dx2 = xb[j * 3 + 2] - xb[i * 3 + 2];
        float d2 = dx0 * dx0 + dx1 * dx1 + dx2 * dx2;
        float nrm = sqrtf(fmaxf(d2, 0.f) + 1e-5f);
        nrm_s[j] = nrm;
        en_s[j] = __expf(-nrm);
        norm_g[(size_t)bi * NN + j] = nrm;
    }
    __syncthreads();

    // ---- phase 1: stage A1 = [rbf*hk | nrm | 0] bf16 (lane = k)
    {
        const int k = tid & 63;
        const int jg = tid >> 6;
        const bool kv = (k < KK);
        const float v_ik = kv ? V[((size_t)b * NN + i) * 64 + k] : 0.f;
        const float mean_k = kv ? means[k] : 0.f;
        const float beta_k = kv ? betas[k] : 0.f;
        for (int jj = 0; jj < 64; jj++) {
            int j = jj * 4 + jg;
            float u = kv ? U[((size_t)b * NN + j) * 64 + k] : 0.f;
            float hk = u + v_ik;
            float e = en_s[j] - mean_k;
            float val = __expf(-beta_k * e * e) * hk;   // k>=50: beta=0, hk=0 -> 0
            if (k == KK) val = nrm_s[j];
            A1[j * 72 + k] = f2bf(val);
        }
    }
    __syncthreads();

    const int col = w * 16 + lcol;       // output channel owned by this lane

    // ---- phase 2: GEMM1 -> s1 = silu(acc + P[j] + Q[i]) -> A2 bf16
    {
        const float q_val = Q[((size_t)b * NN + i) * 64 + col];
        f32x4v acc[16];
#pragma unroll
        for (int mt = 0; mt < 16; mt++) acc[mt] = (f32x4v){0.f, 0.f, 0.f, 0.f};

#pragma unroll
        for (int kb = 0; kb < 2; kb++) {
            const int ko = kb * 32 + quad * 8;
            bf16x8 bfrag = *(const bf16x8*)&Wo1T[col * 64 + ko];
#pragma unroll
            for (int mt = 0; mt < 16; mt++) {
                bf16x8 afrag = *(const bf16x8*)&A1[(mt * 16 + lcol) * 72 + ko];
                acc[mt] = __builtin_amdgcn_mfma_f32_16x16x32_bf16(afrag, bfrag, acc[mt], 0, 0, 0);
            }
        }

#pragma unroll
        for (int mt = 0; mt < 16; mt++) {
#pragma unroll
            for (int reg = 0; reg < 4; reg++) {
                int j = mt * 16 + quad * 4 + reg;
                float pv = P[((size_t)b * NN + j) * 64 + col];
                float s1v = siluf(acc[mt][reg] + pv + q_val);
                A2[j * 72 + col] = f2bf(s1v);
            }
        }
    }
    __syncthreads();

    // ---- phase 3: GEMM2 -> he; write fp32 global + bf16 into A1
    {
        f32x4v acc[16];
#pragma unroll
        for (int mt = 0; mt < 16; mt++) acc[mt] = (f32x4v){0.f, 0.f, 0.f, 0.f};

#pragma unroll
        for (int kb = 0; kb < 2; kb++) {
            const int ko = kb * 32 + quad * 8;
            bf16x8 bfrag = *(const bf16x8*)&Wo2T[col * 64 + ko];
#pragma unroll
            for (int mt = 0; mt < 16; mt++) {
                bf16x8 afrag = *(const bf16x8*)&A2[(mt * 16 + lcol) * 72 + ko];
                acc[mt] = __builtin_amdgcn_mfma_f32_16x16x32_bf16(afrag, bfrag, acc[mt], 0, 0, 0);
            }
        }

#pragma unroll
        for (int mt = 0; mt < 16; mt++) {
#pragma unroll
            for (int reg = 0; reg < 4; reg++) {
                int j = mt * 16 + quad * 4 + reg;
                float hev = acc[mt][reg];
                he_mtx[((size_t)bi * NN + j) * HH + col] = hev;
                A1[j * 72 + col] = f2bf(hev);
            }
        }
    }
    __syncthreads();

    // ---- phase 4: sem logits (thread = j)
    {
        int j = tid;
        const float4* Ws4 = (const float4*)Ws;   // row ch -> 4 heads
        float a0 = bs[0], a1 = bs[1], a2 = bs[2], a3 = bs[3];
#pragma unroll
        for (int c8 = 0; c8 < 64; c8 += 8) {
            bf16x8 hv8 = *(const bf16x8*)&A1[j * 72 + c8];
#pragma unroll
            for (int t = 0; t < 8; t++) {
                float hv = bf2f(hv8[t]);
                float4 wsv = Ws4[c8 + t];
                a0 += hv * wsv.x; a1 += hv * wsv.y;
                a2 += hv * wsv.z; a3 += hv * wsv.w;
            }
        }
        float4 out;
        out.x = a0 > 0.f ? a0 : 2.f * expm1f(0.5f * a0);
        out.y = a1 > 0.f ? a1 : 2.f * expm1f(0.5f * a1);
        out.z = a2 > 0.f ? a2 : 2.f * expm1f(0.5f * a2);
        out.w = a3 > 0.f ? a3 : 2.f * expm1f(0.5f * a3);
        if (i == j) { out.x -= 1e5f; out.y -= 1e5f; out.z -= 1e5f; out.w -= 1e5f; }
        ((float4*)sem_logit)[(size_t)bi * NN + j] = out;
    }
}

// ---------------------------------------------------------------------------
// K2: the three softmaxes over j (round-1 verified).
// ---------------------------------------------------------------------------
__device__ __forceinline__ float4 block_max4(float4 v, float4* buf) {
    int tid = threadIdx.x;
    buf[tid] = v;
    __syncthreads();
    for (int s = 128; s > 0; s >>= 1) {
        if (tid < s) {
            float4 o = buf[tid + s], m = buf[tid];
            m.x = fmaxf(m.x, o.x); m.y = fmaxf(m.y, o.y);
            m.z = fmaxf(m.z, o.z); m.w = fmaxf(m.w, o.w);
            buf[tid] = m;
        }
        __syncthreads();
    }
    float4 r = buf[0];
    __syncthreads();
    return r;
}

__device__ __forceinline__ float4 block_sum4(float4 v, float4* buf) {
    int tid = threadIdx.x;
    buf[tid] = v;
    __syncthreads();
    for (int s = 128; s > 0; s >>= 1) {
        if (tid < s) {
            float4 o = buf[tid + s], m = buf[tid];
            m.x += o.x; m.y += o.y; m.z += o.z; m.w += o.w;
            buf[tid] = m;
        }
        __syncthreads();
    }
    float4 r = buf[0];
    __syncthreads();
    return r;
}

__global__ __launch_bounds__(256) void k2_attn(
    const float* __restrict__ norm_g, const float* __restrict__ sem_logit,
    const float* __restrict__ log_gamma, float* __restrict__ comb_att)
{
    __shared__ float4 buf[256];
    const int bi = blockIdx.x;
    const int i = bi & 255;
    const int j = threadIdx.x;
    const size_t base = (size_t)bi * NN + j;

    float g0 = __expf(log_gamma[0]);
    float g1 = __expf(log_gamma[1]);
    float g2 = __expf(log_gamma[2]);
    float g3 = __expf(log_gamma[3]);

    float nrm = norm_g[base];
    float pen = (j == i) ? 1e5f : 0.f;
    float nl = -(nrm + pen);
    float4 el = make_float4(nl * g0, nl * g1, nl * g2, nl * g3);
    float4 sl = ((const float4*)sem_logit)[base];

    float4 m = block_max4(el, buf);
    float4 ev = make_float4(__expf(el.x - m.x), __expf(el.y - m.y),
                            __expf(el.z - m.z), __expf(el.w - m.w));
    float4 sum = block_sum4(ev, buf);
    float4 eucl = make_float4(ev.x / sum.x, ev.y / sum.y, ev.z / sum.z, ev.w / sum.w);

    m = block_max4(sl, buf);
    float4 sv = make_float4(__expf(sl.x - m.x), __expf(sl.y - m.y),
                            __expf(sl.z - m.z), __expf(sl.w - m.w));
    sum = block_sum4(sv, buf);
    float4 sem = make_float4(sv.x / sum.x, sv.y / sum.y, sv.z / sum.z, sv.w / sum.w);

    float4 cl = make_float4(eucl.x * sem.x, eucl.y * sem.y, eucl.z * sem.z, eucl.w * sem.w);
    m = block_max4(cl, buf);
    float4 cv = make_float4(__expf(cl.x - m.x), __expf(cl.y - m.y),
                            __expf(cl.z - m.z), __expf(cl.w - m.w));
    sum = block_sum4(cv, buf);
    float4 ca = make_float4(cv.x / sum.x, cv.y / sum.y, cv.z / sum.z, cv.w / sum.w);

    ((float4*)comb_att)[base] = ca;
}

// ---------------------------------------------------------------------------
// K3: bf16 MFMA spatial attention, column-split for occupancy.
// Grid = 1024: blockIdx = bi*2 + half; block owns cols half*128..+127.
// Wave tile 64x32 (acc[4][2] = 32 VGPR) -> __launch_bounds__(256,4) keeps
// VGPR <= 128: 4 waves/SIMD; LDS 39424B x 4 = 157696 <= 160 KiB: 4 blk/CU.
// Staging (full 256-col hea) duplicated across the 2 halves (L2-hot).
// h_e computed identically in both halves; half 0 writes. delta_v written
// as per-half partials (dv_part[bi*2+half][3]), summed in k4.
// ---------------------------------------------------------------------------
__global__ __launch_bounds__(256, 4) void k3_spatial(
    const float* __restrict__ he_mtx, const float* __restrict__ comb_att,
    const float* __restrict__ x, const float* __restrict__ norm_g,
    const unsigned short* __restrict__ WxT, const float* __restrict__ Wv_mix,
    float* __restrict__ h_e, float* __restrict__ comb_norm,
    float* __restrict__ dv_part)
{
    __shared__ unsigned short hea[64 * 264];   // 33 KB
    __shared__ float4 xds[64];                 // 1 KB
    __shared__ float red_he[4][CC];            // 4 KB cross-wave h_e partials
    __shared__ float dvbuf[4][3];

    const int tid = threadIdx.x;
    const int l = tid & 63;
    const int w = tid >> 6;
    const int lrow = l >> 4;        // quad 0..3
    const int lcol = l & 15;
    const int bi = blockIdx.x >> 1;
    const int half = blockIdx.x & 1;
    const int wcol = half * 128 + w * 32;   // first of this wave's 32 cols
    const int b = bi >> 8;
    const int i = bi & 255;

    const float* xb = x + (size_t)b * NN * 3;
    const float xi0 = xb[i * 3 + 0], xi1 = xb[i * 3 + 1], xi2 = xb[i * 3 + 2];

    float wv_l[2];
#pragma unroll
    for (int nt = 0; nt < 2; nt++) wv_l[nt] = Wv_mix[wcol + nt * 16 + lcol];

    float cs[2][3] = {{0.f,0.f,0.f},{0.f,0.f,0.f}};
    float dv[3] = {0.f, 0.f, 0.f};
    float he4[4] = {0.f, 0.f, 0.f, 0.f};   // cols 4l..4l+3, this wave's j's

    for (int pass = 0; pass < 4; pass++) {
        const int jt = pass * 64;

        // ---- staging: 16 coalesced rows per wave (full 256-col tile)
#pragma unroll 4
        for (int jj = 0; jj < 16; jj++) {
            const int row = jj * 4 + w;
            const int j = jt + row;
            float hv = he_mtx[((size_t)bi * NN + j) * HH + l];
            float4 av = ((const float4*)comb_att)[(size_t)bi * NN + j];
            float v0 = hv * av.x, v1 = hv * av.y, v2 = hv * av.z, v3 = hv * av.w;
            he4[0] += v0; he4[1] += v1; he4[2] += v2; he4[3] += v3;
            ushort4 pk = make_ushort4(f2bf(v0), f2bf(v1), f2bf(v2), f2bf(v3));
            *(ushort4*)&hea[row * 264 + 4 * l] = pk;
        }
        if (tid < 64) {
            int j = jt + tid;
            float nrm = norm_g[(size_t)bi * NN + j];
            float inv = 1.f / (nrm + 1e-5f);
            xds[tid] = make_float4((xb[j * 3 + 0] - xi0) * inv,
                                   (xb[j * 3 + 1] - xi1) * inv,
                                   (xb[j * 3 + 2] - xi2) * inv, 0.f);
        }
        __syncthreads();

        // ---- MFMA: [64 j] x [256 k] @ WxT -> wave's 32 cols
        f32x4v acc[4][2];
#pragma unroll
        for (int mt = 0; mt < 4; mt++)
#pragma unroll
            for (int nt = 0; nt < 2; nt++)
                acc[mt][nt] = (f32x4v){0.f, 0.f, 0.f, 0.f};

        for (int kb = 0; kb < 8; kb++) {
            const int ko = kb * 32 + lrow * 8;
            bf16x8 af[4], bf[2];
#pragma unroll
            for (int mt = 0; mt < 4; mt++)
                af[mt] = *(const bf16x8*)&hea[(mt * 16 + lcol) * 264 + ko];
#pragma unroll
            for (int nt = 0; nt < 2; nt++)
                bf[nt] = *(const bf16x8*)&WxT[(size_t)(wcol + nt * 16 + lcol) * 256 + ko];
#pragma unroll
            for (int mt = 0; mt < 4; mt++)
#pragma unroll
                for (int nt = 0; nt < 2; nt++)
                    acc[mt][nt] = __builtin_amdgcn_mfma_f32_16x16x32_bf16(
                        af[mt], bf[nt], acc[mt][nt], 0, 0, 0);
        }

        // ---- epilogue: tanh + cs/dv accumulation
#pragma unroll
        for (int mt = 0; mt < 4; mt++) {
#pragma unroll
            for (int reg = 0; reg < 4; reg++) {
                int row = mt * 16 + lrow * 4 + reg;
                float4 xv = xds[row];
#pragma unroll
                for (int nt = 0; nt < 2; nt++) {
                    float coeff = tanh_fast(acc[mt][nt][reg]);
                    float cw = coeff * wv_l[nt];
                    cs[nt][0] += xv.x * coeff; cs[nt][1] += xv.y * coeff; cs[nt][2] += xv.z * coeff;
                    dv[0] += xv.x * cw; dv[1] += xv.y * cw; dv[2] += xv.z * cw;
                }
            }
        }
        __syncthreads();   // protect hea/xds before next pass staging
    }

    // ---- h_e: cross-wave reduce of per-wave column partials (half 0 writes)
    *(float4*)&red_he[w][4 * l] = make_float4(he4[0], he4[1], he4[2], he4[3]);
    __syncthreads();
    if (half == 0) {
        float hv = red_he[0][tid] + red_he[1][tid] + red_he[2][tid] + red_he[3][tid];
        h_e[(size_t)bi * CC + tid] = hv;
    }

    // ---- comb_norm: reduce cs over the 4 row-group lanes (xor 16, 32)
#pragma unroll
    for (int nt = 0; nt < 2; nt++)
#pragma unroll
        for (int t = 0; t < 3; t++) {
            cs[nt][t] += __shfl_xor(cs[nt][t], 16, 64);
            cs[nt][t] += __shfl_xor(cs[nt][t], 32, 64);
        }
    if (lrow == 0) {
        const float invn = 1.f / (float)NN;
#pragma unroll
        for (int nt = 0; nt < 2; nt++) {
            int colx = wcol + nt * 16 + lcol;
            float m0 = cs[nt][0] * invn, m1 = cs[nt][1] * invn, m2 = cs[nt][2] * invn;
            comb_norm[(size_t)bi * CC + colx] = m0 * m0 + m1 * m1 + m2 * m2;
        }
    }

    // ---- delta_v partial: full wave reduce then cross-wave via LDS
#pragma unroll
    for (int t = 0; t < 3; t++)
#pragma unroll
        for (int off = 32; off >= 1; off >>= 1)
            dv[t] += __shfl_xor(dv[t], off, 64);
    if (l == 0) {
        dvbuf[w][0] = dv[0]; dvbuf[w][1] = dv[1]; dvbuf[w][2] = dv[2];
    }
    __syncthreads();
    if (tid < 3) {
        float ssum = dvbuf[0][tid] + dvbuf[1][tid] + dvbuf[2][tid] + dvbuf[3][tid];
        dv_part[(size_t)blockIdx.x * 3 + tid] = ssum * (1.f / (float)NN);
    }
}

// ---------------------------------------------------------------------------
// K4: node MLPs + velocity/position update. delta_v = sum of 2 k3 partials.
// ---------------------------------------------------------------------------
__global__ __launch_bounds__(64) void k4_node(
    const float* __restrict__ h, const float* __restrict__ x, const float* __restrict__ v,
    const float* __restrict__ h_e, const float* __restrict__ comb_norm,
    const float* __restrict__ dv_part,
    const float* __restrict__ Wp1, const float* __restrict__ bp1,
    const float* __restrict__ Wp2, const float* __restrict__ bp2,
    const float* __restrict__ Wn1, const float* __restrict__ bn1,
    const float* __restrict__ Wn2, const float* __restrict__ bn2,
    const float* __restrict__ Wvel1, const float* __restrict__ bvel1,
    const float* __restrict__ Wvel2,
    float* __restrict__ out)
{
    __shared__ float cn[CC];
    __shared__ float inb[FF + CC + HH];
    __shared__ float tmp[HH];
    __shared__ float hn[HH];

    const int bi = blockIdx.x;
    const int t = threadIdx.x;

#pragma unroll
    for (int r = 0; r < 4; r++) {
        cn[r * 64 + t] = comb_norm[(size_t)bi * CC + r * 64 + t];
        inb[FF + r * 64 + t] = h_e[(size_t)bi * CC + r * 64 + t];
    }
    inb[t] = h[(size_t)bi * FF + t];
    __syncthreads();

    float acc = bp1[t];
#pragma unroll 8
    for (int k = 0; k < CC; k++) acc += cn[k] * Wp1[k * HH + t];
    tmp[t] = siluf(acc);
    __syncthreads();
    acc = bp2[t];
#pragma unroll 8
    for (int k = 0; k < HH; k++) acc += tmp[k] * Wp2[k * HH + t];
    inb[FF + CC + t] = siluf(acc);
    __syncthreads();

    acc = bn1[t];
#pragma unroll 8
    for (int k = 0; k < FF + CC + HH; k++) acc += inb[k] * Wn1[k * HH + t];
    float n1v = siluf(acc);
    __syncthreads();
    tmp[t] = n1v;
    __syncthreads();
    acc = bn2[t];
#pragma unroll 8
    for (int k = 0; k < HH; k++) acc += tmp[k] * Wn2[k * FF + t];
    float hnew = inb[t] + siluf(acc);
    hn[t] = hnew;
    out[(size_t)bi * FF + t] = hnew;
    __syncthreads();

    acc = bvel1[t];
#pragma unroll 8
    for (int k = 0; k < HH; k++) acc += hn[k] * Wvel1[k * HH + t];
    float val = siluf(acc) * Wvel2[t];
#pragma unroll
    for (int off = 32; off >= 1; off >>= 1) val += __shfl_xor(val, off, 64);
    float vscale = 2.f * sigmoidf_(val);

    if (t < 3) {
        float vv = v[(size_t)bi * 3 + t];
        float dvsum = dv_part[(size_t)(bi * 2) * 3 + t] + dv_part[(size_t)(bi * 2 + 1) * 3 + t];
        float vn = dvsum + vscale * vv;
        out[32768 + (size_t)bi * 3 + t] = x[(size_t)bi * 3 + t] + vn;  // x_new
        out[34304 + (size_t)bi * 3 + t] = vn;                           // v_new
    }
}

// ---------------------------------------------------------------------------
extern "C" void kernel_launch(void* const* d_in, const int* in_sizes, int n_in,
                              void* d_out, int out_size, void* d_ws, size_t ws_size,
                              hipStream_t stream)
{
    const float* h        = (const float*)d_in[0];
    const float* x        = (const float*)d_in[1];
    const float* v        = (const float*)d_in[2];
    const float* means    = (const float*)d_in[3];
    const float* betas    = (const float*)d_in[4];
    const float* W_in     = (const float*)d_in[5];
    const float* b_in     = (const float*)d_in[6];
    const float* W_o1     = (const float*)d_in[7];
    const float* b_o1     = (const float*)d_in[8];
    const float* W_o2     = (const float*)d_in[9];
    const float* b_o2     = (const float*)d_in[10];
    const float* Ws       = (const float*)d_in[11];
    const float* bs       = (const float*)d_in[12];
    const float* log_gamma= (const float*)d_in[13];
    const float* Wx       = (const float*)d_in[14];
    const float* Wp1      = (const float*)d_in[15];
    const float* bp1      = (const float*)d_in[16];
    const float* Wp2      = (const float*)d_in[17];
    const float* bp2      = (const float*)d_in[18];
    const float* Wn1      = (const float*)d_in[19];
    const float* bn1      = (const float*)d_in[20];
    const float* Wn2      = (const float*)d_in[21];
    const float* bn2      = (const float*)d_in[22];
    const float* Wv_mix   = (const float*)d_in[23];
    const float* Wvel1    = (const float*)d_in[24];
    const float* bvel1    = (const float*)d_in[25];
    const float* Wvel2    = (const float*)d_in[26];

    float* ws = (float*)d_ws;
    float* norm_g    = ws;                 // 131072
    float* he_mtx    = ws + 131072;        // 8388608
    float* sem_logit = ws + 8519680;       // 524288 (WxT bf16 aliased after k2)
    float* comb_att  = ws + 9043968;       // 524288 (UVPQ + Wo1T/Wo2T aliased pre-k2)
    float* h_e       = ws + 9568256;       // 131072
    float* comb_norm = ws + 9699328;       // 131072
    float* dv_part   = ws + 9830400;       // 3072 (1024 blocks x 3)

    // Pre-k2 aliases in the comb_att region (dead until k2 writes it):
    float* U = comb_att;                   // 512*64
    float* V = comb_att + 32768;
    float* P = comb_att + 65536;
    float* Q = comb_att + 98304;
    unsigned short* Wo1T = (unsigned short*)(comb_att + 131072);  // 4096 shorts
    unsigned short* Wo2T = (unsigned short*)(comb_att + 133120);  // 4096 shorts

    // WxT bf16 aliases sem_logit (dead after k2; k0b runs after k2).
    unsigned short* WxT = (unsigned short*)sem_logit;

    k0_node_pre<<<dim3(BN), dim3(64), 0, stream>>>(
        h, W_in, b_in, W_o1, b_o1, U, V, P, Q);

    k0c_wtrans<<<dim3(16), dim3(256), 0, stream>>>(W_o1, W_o2, Wo1T, Wo2T);

    k1_edge_mfma<<<dim3(BN), dim3(256), 0, stream>>>(
        x, means, betas, U, V, P, Q, Wo1T, Wo2T, Ws, bs,
        he_mtx, sem_logit, norm_g);

    k2_attn<<<dim3(BN), dim3(256), 0, stream>>>(norm_g, sem_logit, log_gamma, comb_att);

    k0b_wxt<<<dim3(256), dim3(256), 0, stream>>>(Wx, WxT);

    k3_spatial<<<dim3(BN * 2), dim3(256), 0, stream>>>(
        he_mtx, comb_att, x, norm_g, WxT, Wv_mix, h_e, comb_norm, dv_part);

    k4_node<<<dim3(BN), dim3(64), 0, stream>>>(
        h, x, v, h_e, comb_norm, dv_part,
        Wp1, bp1, Wp2, bp2, Wn1, bn1, Wn2, bn2, Wvel1, bvel1, Wvel2,
        (float*)d_out);
}